// Round 1
// baseline (561.589 us; speedup 1.0000x reference)
//
#include <hip/hip_runtime.h>
#include <math.h>

#define NROW 4096
#define FDIM 512
#define MARGIN 1.0f

// ---------------------------------------------------------------------------
// Kernel 1: row norms  na[j] = ||a_j||^2, nb[i] = ||b_i||^2
// one wave per row, float4 loads
// ---------------------------------------------------------------------------
__global__ __launch_bounds__(64) void norms_kernel(const float* __restrict__ a,
                                                   const float* __restrict__ b,
                                                   float* __restrict__ na,
                                                   float* __restrict__ nb) {
    int row  = blockIdx.x;
    int lane = threadIdx.x;
    const float4* a4 = (const float4*)(a + (size_t)row * FDIM);
    const float4* b4 = (const float4*)(b + (size_t)row * FDIM);
    float sa = 0.f, sb = 0.f;
    #pragma unroll
    for (int f = lane; f < FDIM / 4; f += 64) {
        float4 va = a4[f];
        sa += va.x * va.x + va.y * va.y + va.z * va.z + va.w * va.w;
        float4 vb = b4[f];
        sb += vb.x * vb.x + vb.y * vb.y + vb.z * vb.z + vb.w * vb.w;
    }
    #pragma unroll
    for (int o = 32; o > 0; o >>= 1) {
        sa += __shfl_down(sa, o);
        sb += __shfl_down(sb, o);
    }
    if (lane == 0) { na[row] = sa; nb[row] = sb; }
}

// ---------------------------------------------------------------------------
// Pass kernels: 64x64 tile of S = b @ a^T, fused epilogue.
// PHASE 1: row_negsum[i] += sum_j (labels differ) exp(MARGIN - D[i,j])
// PHASE 2: loss_sum += sum over pos pairs max(log(rns_i+rns_j)+D, 0)^2
// block = 256 threads = 16x16, each thread computes a 4x4 micro-tile.
// ---------------------------------------------------------------------------
template <int PHASE>
__global__ __launch_bounds__(256) void pass_kernel(
    const float* __restrict__ a, const float* __restrict__ b,
    const int* __restrict__ labels,
    const float* __restrict__ na, const float* __restrict__ nb,
    float* __restrict__ rns, float* __restrict__ loss_sum)
{
    // k-major tiles; row stride 68 floats = 272 B (16B aligned, conflict-benign)
    __shared__ float As[16][68];
    __shared__ float Bs[16][68];

    const int t  = threadIdx.x;
    const int tx = t & 15;
    const int ty = t >> 4;
    const int ti = blockIdx.y * 64;   // b-row (i) tile origin
    const int tj = blockIdx.x * 64;   // a-row (j) tile origin

    float acc[4][4] = {};

    for (int kk = 0; kk < FDIM; kk += 16) {
        #pragma unroll
        for (int l = 0; l < 4; ++l) {
            int idx = t + l * 256;     // 0..1023
            int r   = idx >> 4;        // tile row 0..63
            int k   = idx & 15;        // k within chunk
            As[k][r] = a[(size_t)(tj + r) * FDIM + kk + k];
            Bs[k][r] = b[(size_t)(ti + r) * FDIM + kk + k];
        }
        __syncthreads();
        #pragma unroll
        for (int k = 0; k < 16; ++k) {
            float4 bi4 = *(const float4*)&Bs[k][ty * 4];
            float4 aj4 = *(const float4*)&As[k][tx * 4];
            float bb[4] = {bi4.x, bi4.y, bi4.z, bi4.w};
            float aa[4] = {aj4.x, aj4.y, aj4.z, aj4.w};
            #pragma unroll
            for (int ii = 0; ii < 4; ++ii)
                #pragma unroll
                for (int jj = 0; jj < 4; ++jj)
                    acc[ii][jj] += bb[ii] * aa[jj];
        }
        __syncthreads();
    }

    const int i0 = ti + ty * 4;
    const int j0 = tj + tx * 4;
    int   li[4], lj[4];
    float nbv[4], nav[4];
    #pragma unroll
    for (int ii = 0; ii < 4; ++ii) { li[ii] = labels[i0 + ii]; nbv[ii] = nb[i0 + ii]; }
    #pragma unroll
    for (int jj = 0; jj < 4; ++jj) { lj[jj] = labels[j0 + jj]; nav[jj] = na[j0 + jj]; }

    if (PHASE == 1) {
        #pragma unroll
        for (int ii = 0; ii < 4; ++ii) {
            float rs = 0.f;
            #pragma unroll
            for (int jj = 0; jj < 4; ++jj) {
                float dsq = nbv[ii] + nav[jj] - 2.f * acc[ii][jj];
                float D   = sqrtf(fmaxf(dsq, 0.f));
                if (li[ii] != lj[jj]) rs += __expf(MARGIN - D);
            }
            // reduce across the 16 tx lanes sharing this row
            #pragma unroll
            for (int o = 8; o > 0; o >>= 1) rs += __shfl_down(rs, o, 16);
            if (tx == 0) atomicAdd(&rns[i0 + ii], rs);
        }
    } else {
        float rbi[4], rbj[4];
        #pragma unroll
        for (int ii = 0; ii < 4; ++ii) rbi[ii] = rns[i0 + ii];
        #pragma unroll
        for (int jj = 0; jj < 4; ++jj) rbj[jj] = rns[j0 + jj];
        float local = 0.f;
        #pragma unroll
        for (int ii = 0; ii < 4; ++ii)
            #pragma unroll
            for (int jj = 0; jj < 4; ++jj) {
                int i = i0 + ii, j = j0 + jj;
                if (li[ii] == lj[jj] && i != j) {
                    float dsq = nbv[ii] + nav[jj] - 2.f * acc[ii][jj];
                    float D   = sqrtf(fmaxf(dsq, 0.f));
                    float J   = __logf(rbi[ii] + rbj[jj]) + D;
                    float h   = fmaxf(J, 0.f);
                    local += h * h;
                }
            }
        // block reduce: wave shuffle, then 4 partials in LDS
        #pragma unroll
        for (int o = 32; o > 0; o >>= 1) local += __shfl_down(local, o);
        __shared__ float part[4];
        if ((t & 63) == 0) part[t >> 6] = local;
        __syncthreads();
        if (t == 0) atomicAdd(loss_sum, part[0] + part[1] + part[2] + part[3]);
    }
}

// ---------------------------------------------------------------------------
// Finalize: num_pos from label histogram; out = loss_sum / (2*num_pos)
// ---------------------------------------------------------------------------
__global__ __launch_bounds__(256) void finalize_kernel(const int* __restrict__ labels,
                                                       const float* __restrict__ loss_sum,
                                                       float* __restrict__ out) {
    __shared__ int hist[16];
    int t = threadIdx.x;
    if (t < 16) hist[t] = 0;
    __syncthreads();
    for (int i = t; i < NROW; i += 256) atomicAdd(&hist[labels[i] & 15], 1);
    __syncthreads();
    if (t == 0) {
        long long np = 0;
        for (int c = 0; c < 16; ++c) np += (long long)hist[c] * (long long)(hist[c] - 1);
        out[0] = loss_sum[0] / (2.0f * (float)np);
    }
}

// ---------------------------------------------------------------------------
extern "C" void kernel_launch(void* const* d_in, const int* in_sizes, int n_in,
                              void* d_out, int out_size, void* d_ws, size_t ws_size,
                              hipStream_t stream) {
    const float* a      = (const float*)d_in[0];
    const float* b      = (const float*)d_in[1];
    const int*   labels = (const int*)d_in[2];
    float* out = (float*)d_out;

    float* ws   = (float*)d_ws;
    float* na   = ws;                 // [4096]
    float* nb   = ws + NROW;          // [4096]
    float* rns  = ws + 2 * NROW;      // [4096]
    float* loss = ws + 3 * NROW;      // [1]

    // zero rns + loss (ws is re-poisoned to 0xAA before every timed launch)
    hipMemsetAsync(rns, 0, (NROW + 1) * sizeof(float), stream);

    norms_kernel<<<NROW, 64, 0, stream>>>(a, b, na, nb);

    dim3 grid(NROW / 64, NROW / 64);
    pass_kernel<1><<<grid, 256, 0, stream>>>(a, b, labels, na, nb, rns, loss);
    pass_kernel<2><<<grid, 256, 0, stream>>>(a, b, labels, na, nb, rns, loss);

    finalize_kernel<<<1, 256, 0, stream>>>(labels, loss, out);
}

// Round 2
// 174.810 us; speedup vs baseline: 3.2126x; 3.2126x over previous
//
#include <hip/hip_runtime.h>
#include <math.h>

#define NROW 4096
#define FDIM 512
#define MARGIN 1.0f

typedef __attribute__((ext_vector_type(8))) short short8;
typedef __attribute__((ext_vector_type(4))) float floatx4;

// round-to-nearest-even fp32 -> bf16 (inputs are finite gaussians, no NaN)
__device__ inline unsigned short f2bf(float x) {
    unsigned u = __float_as_uint(x);
    return (unsigned short)((u + 0x7FFFu + ((u >> 16) & 1u)) >> 16);
}

// ---------------------------------------------------------------------------
// Convert a, b (fp32) -> bf16 arrays in workspace. 1 float4 per thread each.
// ---------------------------------------------------------------------------
__global__ __launch_bounds__(256) void convert_kernel(
    const float* __restrict__ a, const float* __restrict__ b,
    unsigned short* __restrict__ abf, unsigned short* __restrict__ bbf) {
    int idx = blockIdx.x * 256 + threadIdx.x;      // 0 .. (4096*512/4 - 1)
    float4 va = ((const float4*)a)[idx];
    float4 vb = ((const float4*)b)[idx];
    ushort4 ua = { f2bf(va.x), f2bf(va.y), f2bf(va.z), f2bf(va.w) };
    ushort4 ub = { f2bf(vb.x), f2bf(vb.y), f2bf(vb.z), f2bf(vb.w) };
    ((ushort4*)abf)[idx] = ua;
    ((ushort4*)bbf)[idx] = ub;
}

// ---------------------------------------------------------------------------
// Row norms in fp32 (exact, from the original fp32 inputs)
// ---------------------------------------------------------------------------
__global__ __launch_bounds__(64) void norms_kernel(const float* __restrict__ a,
                                                   const float* __restrict__ b,
                                                   float* __restrict__ na,
                                                   float* __restrict__ nb) {
    int row  = blockIdx.x;
    int lane = threadIdx.x;
    const float4* a4 = (const float4*)(a + (size_t)row * FDIM);
    const float4* b4 = (const float4*)(b + (size_t)row * FDIM);
    float sa = 0.f, sb = 0.f;
    #pragma unroll
    for (int f = lane; f < FDIM / 4; f += 64) {
        float4 va = a4[f];
        sa += va.x * va.x + va.y * va.y + va.z * va.z + va.w * va.w;
        float4 vb = b4[f];
        sb += vb.x * vb.x + vb.y * vb.y + vb.z * vb.z + vb.w * vb.w;
    }
    #pragma unroll
    for (int o = 32; o > 0; o >>= 1) {
        sa += __shfl_down(sa, o);
        sb += __shfl_down(sb, o);
    }
    if (lane == 0) { na[row] = sa; nb[row] = sb; }
}

// ---------------------------------------------------------------------------
// MFMA pass kernel: 128x128 tile of S = b @ a^T via mfma_f32_16x16x32_bf16.
// 256 threads = 4 waves arranged 2x2; each wave owns a 64x64 block (4x4 MFMAs).
// PHASE 1: rns[i] += sum_j{labels differ} exp(MARGIN - D)
// PHASE 2: loss_sum += sum over positive pairs max(log(rns_i+rns_j)+D, 0)^2
// ---------------------------------------------------------------------------
template <int PHASE>
__global__ __launch_bounds__(256) void pass_mfma(
    const unsigned short* __restrict__ abf, const unsigned short* __restrict__ bbf,
    const int* __restrict__ labels,
    const float* __restrict__ na, const float* __restrict__ nb,
    float* __restrict__ rns, float* __restrict__ loss_sum)
{
    // k-major unpadded tiles (global_load_lds requires chunk-contiguous layout)
    __shared__ __align__(16) unsigned short As[128 * 32];  // a-rows (j), 8 KB
    __shared__ __align__(16) unsigned short Bs[128 * 32];  // b-rows (i), 8 KB
    __shared__ int   li_s[128], lj_s[128];
    __shared__ float nb_s[128], na_s[128], rbi_s[128], rbj_s[128];

    const int t    = threadIdx.x;
    const int lane = t & 63;
    const int w    = t >> 6;
    const int wi   = w >> 1, wj = w & 1;      // 2x2 wave grid
    const int ti   = blockIdx.y * 128;        // b-row (i) origin
    const int tj   = blockIdx.x * 128;        // a-row (j) origin
    const int lr   = lane & 15;               // col-within-16 / row-within-16
    const int lq   = lane >> 4;               // quad

    floatx4 acc[4][4];
    #pragma unroll
    for (int i = 0; i < 4; ++i)
        #pragma unroll
        for (int j = 0; j < 4; ++j)
            acc[i][j] = (floatx4){0.f, 0.f, 0.f, 0.f};

    // stage per-tile metadata (first __syncthreads below covers the hazard)
    if (t < 128) {
        li_s[t] = labels[ti + t];
        nb_s[t] = nb[ti + t];
        if (PHASE == 2) rbi_s[t] = rns[ti + t];
    } else {
        int u = t - 128;
        lj_s[u] = labels[tj + u];
        na_s[u] = na[tj + u];
        if (PHASE == 2) rbj_s[u] = rns[tj + u];
    }

    for (int kk = 0; kk < FDIM; kk += 32) {
        // stage: 512 x 16B chunks per tile; LDS dest = chunk-contiguous
        #pragma unroll
        for (int l = 0; l < 2; ++l) {
            int c    = t + l * 256;          // 0..511
            int row  = c >> 2;
            int quad = c & 3;
            const unsigned short* ga = abf + (size_t)(tj + row) * FDIM + kk + quad * 8;
            const unsigned short* gb = bbf + (size_t)(ti + row) * FDIM + kk + quad * 8;
            __builtin_amdgcn_global_load_lds(
                (const __attribute__((address_space(1))) unsigned int*)ga,
                (__attribute__((address_space(3))) unsigned int*)(As + (size_t)c * 8),
                16, 0, 0);
            __builtin_amdgcn_global_load_lds(
                (const __attribute__((address_space(1))) unsigned int*)gb,
                (__attribute__((address_space(3))) unsigned int*)(Bs + (size_t)c * 8),
                16, 0, 0);
        }
        __syncthreads();

        // fragments: A-operand holds b-rows (output rows i), B-operand a-rows (cols j)
        // layout: element [m=lane&15][k=quad*8+j] -> 16B contiguous in k-major LDS
        short8 af[4], bf[4];
        #pragma unroll
        for (int ri = 0; ri < 4; ++ri)
            af[ri] = *(const short8*)&Bs[(wi * 64 + ri * 16 + lr) * 32 + lq * 8];
        #pragma unroll
        for (int rj = 0; rj < 4; ++rj)
            bf[rj] = *(const short8*)&As[(wj * 64 + rj * 16 + lr) * 32 + lq * 8];

        #pragma unroll
        for (int ri = 0; ri < 4; ++ri)
            #pragma unroll
            for (int rj = 0; rj < 4; ++rj)
                acc[ri][rj] = __builtin_amdgcn_mfma_f32_16x16x32_bf16(
                    af[ri], bf[rj], acc[ri][rj], 0, 0, 0);
        __syncthreads();
    }

    // ---- epilogue: C/D layout col = lane&15, row = quad*4 + reg ----
    if (PHASE == 1) {
        #pragma unroll
        for (int ri = 0; ri < 4; ++ri) {
            float rs[4] = {0.f, 0.f, 0.f, 0.f};
            #pragma unroll
            for (int rj = 0; rj < 4; ++rj) {
                int   jl  = wj * 64 + rj * 16 + lr;
                float naj = na_s[jl];
                int   ljv = lj_s[jl];
                #pragma unroll
                for (int r = 0; r < 4; ++r) {
                    int   il  = wi * 64 + ri * 16 + lq * 4 + r;
                    float dsq = nb_s[il] + naj - 2.f * acc[ri][rj][r];
                    float D   = sqrtf(fmaxf(dsq, 0.f));
                    if (li_s[il] != ljv) rs[r] += __expf(MARGIN - D);
                }
            }
            #pragma unroll
            for (int r = 0; r < 4; ++r) {
                #pragma unroll
                for (int o = 8; o > 0; o >>= 1) rs[r] += __shfl_down(rs[r], o, 16);
            }
            if (lr == 0) {
                #pragma unroll
                for (int r = 0; r < 4; ++r)
                    atomicAdd(&rns[ti + wi * 64 + ri * 16 + lq * 4 + r], rs[r]);
            }
        }
    } else {
        float local = 0.f;
        #pragma unroll
        for (int ri = 0; ri < 4; ++ri)
            #pragma unroll
            for (int rj = 0; rj < 4; ++rj) {
                int jl  = wj * 64 + rj * 16 + lr;
                int ljv = lj_s[jl];
                float naj = na_s[jl], rbj = rbj_s[jl];
                #pragma unroll
                for (int r = 0; r < 4; ++r) {
                    int il = wi * 64 + ri * 16 + lq * 4 + r;
                    int i  = ti + il, j = tj + jl;
                    if (li_s[il] == ljv && i != j) {
                        float dsq = nb_s[il] + naj - 2.f * acc[ri][rj][r];
                        float D   = sqrtf(fmaxf(dsq, 0.f));
                        float J   = __logf(rbi_s[il] + rbj) + D;
                        float h   = fmaxf(J, 0.f);
                        local += h * h;
                    }
                }
            }
        #pragma unroll
        for (int o = 32; o > 0; o >>= 1) local += __shfl_down(local, o);
        __shared__ float part[4];
        if (lane == 0) part[w] = local;
        __syncthreads();
        if (t == 0) atomicAdd(loss_sum, part[0] + part[1] + part[2] + part[3]);
    }
}

// ---------------------------------------------------------------------------
__global__ __launch_bounds__(256) void finalize_kernel(const int* __restrict__ labels,
                                                       const float* __restrict__ loss_sum,
                                                       float* __restrict__ out) {
    __shared__ int hist[16];
    int t = threadIdx.x;
    if (t < 16) hist[t] = 0;
    __syncthreads();
    for (int i = t; i < NROW; i += 256) atomicAdd(&hist[labels[i] & 15], 1);
    __syncthreads();
    if (t == 0) {
        long long np = 0;
        for (int c = 0; c < 16; ++c) np += (long long)hist[c] * (long long)(hist[c] - 1);
        out[0] = loss_sum[0] / (2.0f * (float)np);
    }
}

// ---------------------------------------------------------------------------
extern "C" void kernel_launch(void* const* d_in, const int* in_sizes, int n_in,
                              void* d_out, int out_size, void* d_ws, size_t ws_size,
                              hipStream_t stream) {
    const float* a      = (const float*)d_in[0];
    const float* b      = (const float*)d_in[1];
    const int*   labels = (const int*)d_in[2];
    float* out = (float*)d_out;

    // workspace layout: bf16 a (8 MB) | bf16 b (8 MB) | na | nb | rns | loss
    unsigned short* abf = (unsigned short*)d_ws;
    unsigned short* bbf = abf + (size_t)NROW * FDIM;
    float* fws  = (float*)(bbf + (size_t)NROW * FDIM);
    float* na   = fws;
    float* nb   = fws + NROW;
    float* rns  = fws + 2 * NROW;
    float* loss = fws + 3 * NROW;

    hipMemsetAsync(rns, 0, (NROW + 1) * sizeof(float), stream);

    convert_kernel<<<NROW * FDIM / 4 / 256, 256, 0, stream>>>(a, b, abf, bbf);
    norms_kernel<<<NROW, 64, 0, stream>>>(a, b, na, nb);

    dim3 grid(NROW / 128, NROW / 128);
    pass_mfma<1><<<grid, 256, 0, stream>>>(abf, bbf, labels, na, nb, rns, loss);
    pass_mfma<2><<<grid, 256, 0, stream>>>(abf, bbf, labels, na, nb, rns, loss);

    finalize_kernel<<<1, 256, 0, stream>>>(labels, loss, out);
}

// Round 4
// 168.819 us; speedup vs baseline: 3.3266x; 1.0355x over previous
//
#include <hip/hip_runtime.h>
#include <math.h>

#define NROW 4096
#define FDIM 512
#define MARGIN 1.0f

typedef __attribute__((ext_vector_type(8))) short short8;
typedef __attribute__((ext_vector_type(4))) float floatx4;

__device__ inline unsigned short f2bf(float x) {
    unsigned u = __float_as_uint(x);
    return (unsigned short)((u + 0x7FFFu + ((u >> 16) & 1u)) >> 16);
}
__device__ inline float h2f(unsigned short u) {
    _Float16 h; __builtin_memcpy(&h, &u, 2); return (float)h;
}
__device__ inline unsigned short f2h(float f) {
    _Float16 h = (_Float16)f; unsigned short u; __builtin_memcpy(&u, &h, 2); return u;
}

// ---------------------------------------------------------------------------
// Fused prep: bf16 convert + row norms + zero rns/loss. One wave per row.
// ---------------------------------------------------------------------------
__global__ __launch_bounds__(64) void prep_kernel(
    const float* __restrict__ a, const float* __restrict__ b,
    unsigned short* __restrict__ abf, unsigned short* __restrict__ bbf,
    float* __restrict__ na, float* __restrict__ nb,
    float* __restrict__ rns, float* __restrict__ loss) {
    int row  = blockIdx.x;
    int lane = threadIdx.x;
    const float4* a4 = (const float4*)(a + (size_t)row * FDIM);
    const float4* b4 = (const float4*)(b + (size_t)row * FDIM);
    ushort4* au = (ushort4*)(abf + (size_t)row * FDIM);
    ushort4* bu = (ushort4*)(bbf + (size_t)row * FDIM);
    float sa = 0.f, sb = 0.f;
    #pragma unroll
    for (int f = lane; f < FDIM / 4; f += 64) {
        float4 va = a4[f];
        float4 vb = b4[f];
        sa += va.x * va.x + va.y * va.y + va.z * va.z + va.w * va.w;
        sb += vb.x * vb.x + vb.y * vb.y + vb.z * vb.z + vb.w * vb.w;
        ushort4 ua = { f2bf(va.x), f2bf(va.y), f2bf(va.z), f2bf(va.w) };
        ushort4 ub = { f2bf(vb.x), f2bf(vb.y), f2bf(vb.z), f2bf(vb.w) };
        au[f] = ua;
        bu[f] = ub;
    }
    #pragma unroll
    for (int o = 32; o > 0; o >>= 1) {
        sa += __shfl_down(sa, o);
        sb += __shfl_down(sb, o);
    }
    if (lane == 0) {
        na[row] = sa;
        nb[row] = sb;
        rns[row] = 0.f;
        if (row == 0) loss[0] = 0.f;
    }
}

// ---------------------------------------------------------------------------
// MFMA pass: 128x128 tile of S = b @ a^T, BK=64 (two BK=32 sub-buffers per
// barrier), 4 waves in 2x2, 16x16x32 bf16 MFMA.
// MODE 0: phase1 (negsum) + store D tile (fp16) to workspace
// MODE 1: phase1 only                   (fallback when ws too small)
// MODE 2: phase2 recompute + hinge^2    (fallback)
// ---------------------------------------------------------------------------
template <int MODE>
__global__ __launch_bounds__(256) void pass_mfma(
    const unsigned short* __restrict__ abf, const unsigned short* __restrict__ bbf,
    const int* __restrict__ labels,
    const float* __restrict__ na, const float* __restrict__ nb,
    float* __restrict__ rns, unsigned short* __restrict__ Dws,
    float* __restrict__ loss_sum)
{
    // 32 KB arena: 4 x 8KB k-major sub-tiles during GEMM; fp16 D tile after.
    __shared__ __align__(16) unsigned short smem[16384];
    unsigned short* As0 = smem;
    unsigned short* As1 = smem + 4096;
    unsigned short* Bs0 = smem + 8192;
    unsigned short* Bs1 = smem + 12288;
    __shared__ int   li_s[128], lj_s[128];
    __shared__ float nb_s[128], na_s[128], rbi_s[128], rbj_s[128];

    const int t    = threadIdx.x;
    const int lane = t & 63;
    const int w    = t >> 6;
    const int wi   = w >> 1, wj = w & 1;
    // supertile swizzle: 8x8 blocks per supertile for XCD/L2 locality
    const int bid  = blockIdx.x;
    const int sup  = bid >> 6, loc = bid & 63;
    const int by   = ((sup >> 2) << 3) | (loc >> 3);
    const int bx   = ((sup & 3) << 3) | (loc & 7);
    const int ti   = by * 128;           // b-row (i) origin
    const int tj   = bx * 128;           // a-row (j) origin
    const int lr   = lane & 15;
    const int lq   = lane >> 4;

    floatx4 acc[4][4];
    #pragma unroll
    for (int i = 0; i < 4; ++i)
        #pragma unroll
        for (int j = 0; j < 4; ++j)
            acc[i][j] = (floatx4){0.f, 0.f, 0.f, 0.f};

    if (t < 128) {
        li_s[t] = labels[ti + t];
        nb_s[t] = nb[ti + t];
        if (MODE == 2) rbi_s[t] = rns[ti + t];
    } else {
        int u = t - 128;
        lj_s[u] = labels[tj + u];
        na_s[u] = na[tj + u];
        if (MODE == 2) rbj_s[u] = rns[tj + u];
    }

    for (int kk = 0; kk < FDIM; kk += 64) {
        #pragma unroll
        for (int l = 0; l < 2; ++l) {
            int c   = t + l * 256;       // 0..511
            int row = c >> 2;
            int q   = c & 3;
            size_t ga = (size_t)(tj + row) * FDIM + kk + q * 8;
            size_t gb = (size_t)(ti + row) * FDIM + kk + q * 8;
            __builtin_amdgcn_global_load_lds(
                (const __attribute__((address_space(1))) unsigned int*)(abf + ga),
                (__attribute__((address_space(3))) unsigned int*)(As0 + c * 8), 16, 0, 0);
            __builtin_amdgcn_global_load_lds(
                (const __attribute__((address_space(1))) unsigned int*)(abf + ga + 32),
                (__attribute__((address_space(3))) unsigned int*)(As1 + c * 8), 16, 0, 0);
            __builtin_amdgcn_global_load_lds(
                (const __attribute__((address_space(1))) unsigned int*)(bbf + gb),
                (__attribute__((address_space(3))) unsigned int*)(Bs0 + c * 8), 16, 0, 0);
            __builtin_amdgcn_global_load_lds(
                (const __attribute__((address_space(1))) unsigned int*)(bbf + gb + 32),
                (__attribute__((address_space(3))) unsigned int*)(Bs1 + c * 8), 16, 0, 0);
        }
        __syncthreads();

        {   // k half 0
            short8 af[4], bf[4];
            #pragma unroll
            for (int ri = 0; ri < 4; ++ri)
                af[ri] = *(const short8*)&Bs0[(wi * 64 + ri * 16 + lr) * 32 + lq * 8];
            #pragma unroll
            for (int rj = 0; rj < 4; ++rj)
                bf[rj] = *(const short8*)&As0[(wj * 64 + rj * 16 + lr) * 32 + lq * 8];
            #pragma unroll
            for (int ri = 0; ri < 4; ++ri)
                #pragma unroll
                for (int rj = 0; rj < 4; ++rj)
                    acc[ri][rj] = __builtin_amdgcn_mfma_f32_16x16x32_bf16(
                        af[ri], bf[rj], acc[ri][rj], 0, 0, 0);
        }
        {   // k half 1
            short8 af[4], bf[4];
            #pragma unroll
            for (int ri = 0; ri < 4; ++ri)
                af[ri] = *(const short8*)&Bs1[(wi * 64 + ri * 16 + lr) * 32 + lq * 8];
            #pragma unroll
            for (int rj = 0; rj < 4; ++rj)
                bf[rj] = *(const short8*)&As1[(wj * 64 + rj * 16 + lr) * 32 + lq * 8];
            #pragma unroll
            for (int ri = 0; ri < 4; ++ri)
                #pragma unroll
                for (int rj = 0; rj < 4; ++rj)
                    acc[ri][rj] = __builtin_amdgcn_mfma_f32_16x16x32_bf16(
                        af[ri], bf[rj], acc[ri][rj], 0, 0, 0);
        }
        __syncthreads();
    }

    if (MODE == 0 || MODE == 1) {
        // phase-1 epilogue: C/D layout col = lane&15, row = quad*4 + reg
        unsigned short* D_s = smem;       // 128x128 fp16 tile (32 KB), aliases A/B
        #pragma unroll
        for (int ri = 0; ri < 4; ++ri) {
            float rs[4] = {0.f, 0.f, 0.f, 0.f};
            #pragma unroll
            for (int rj = 0; rj < 4; ++rj) {
                int   jl  = wj * 64 + rj * 16 + lr;
                float naj = na_s[jl];
                int   ljv = lj_s[jl];
                #pragma unroll
                for (int r = 0; r < 4; ++r) {
                    int   il  = wi * 64 + ri * 16 + lq * 4 + r;
                    float dsq = nb_s[il] + naj - 2.f * acc[ri][rj][r];
                    float D   = sqrtf(fmaxf(dsq, 0.f));
                    if (li_s[il] != ljv) rs[r] += __expf(MARGIN - D);
                    if (MODE == 0) D_s[il * 128 + jl] = f2h(D);
                }
            }
            #pragma unroll
            for (int r = 0; r < 4; ++r) {
                #pragma unroll
                for (int o = 8; o > 0; o >>= 1) rs[r] += __shfl_down(rs[r], o, 16);
            }
            if (lr == 0) {
                #pragma unroll
                for (int r = 0; r < 4; ++r)
                    atomicAdd(&rns[ti + wi * 64 + ri * 16 + lq * 4 + r], rs[r]);
            }
        }
        if (MODE == 0) {
            __syncthreads();
            // coalesced fp16 D tile writeout, 16B per thread-chunk
            #pragma unroll
            for (int l = 0; l < 8; ++l) {
                int c  = t + l * 256;     // 0..2047
                int r  = c >> 4;
                int cw = c & 15;
                *(short8*)&Dws[(size_t)(ti + r) * NROW + tj + cw * 8] =
                    *(const short8*)&D_s[r * 128 + cw * 8];
            }
        }
    } else {
        // phase-2 recompute epilogue
        float local = 0.f;
        #pragma unroll
        for (int ri = 0; ri < 4; ++ri)
            #pragma unroll
            for (int rj = 0; rj < 4; ++rj) {
                int jl  = wj * 64 + rj * 16 + lr;
                int ljv = lj_s[jl];
                float naj = na_s[jl], rbj = rbj_s[jl];
                #pragma unroll
                for (int r = 0; r < 4; ++r) {
                    int il = wi * 64 + ri * 16 + lq * 4 + r;
                    int i  = ti + il, j = tj + jl;
                    if (li_s[il] == ljv && i != j) {
                        float dsq = nb_s[il] + naj - 2.f * acc[ri][rj][r];
                        float D   = sqrtf(fmaxf(dsq, 0.f));
                        float J   = __logf(rbi_s[il] + rbj) + D;
                        float h   = fmaxf(J, 0.f);
                        local += h * h;
                    }
                }
            }
        #pragma unroll
        for (int o = 32; o > 0; o >>= 1) local += __shfl_down(local, o);
        __shared__ float part[4];
        if (lane == 0) part[w] = local;
        __syncthreads();
        if (t == 0) atomicAdd(loss_sum, part[0] + part[1] + part[2] + part[3]);
    }
}

// ---------------------------------------------------------------------------
// Light phase 2: sweep stored D (fp16), hinge^2 on positive pairs.
// One block per 16 rows; labels+rns staged in LDS.
// ---------------------------------------------------------------------------
__global__ __launch_bounds__(256) void pass2_light(
    const unsigned short* __restrict__ Dws, const int* __restrict__ labels,
    const float* __restrict__ rns, float* __restrict__ loss_sum)
{
    __shared__ int   lab_s[NROW];
    __shared__ float rns_s[NROW];
    int t = threadIdx.x;
    #pragma unroll
    for (int l = 0; l < NROW / 256; ++l) {
        int idx = t + l * 256;
        lab_s[idx] = labels[idx];
        rns_s[idx] = rns[idx];
    }
    __syncthreads();
    float local = 0.f;
    int i0 = blockIdx.x * 16;
    for (int r = 0; r < 16; ++r) {
        int   i   = i0 + r;
        int   li  = lab_s[i];
        float rbi = rns_s[i];
        const unsigned short* drow = Dws + (size_t)i * NROW;
        #pragma unroll
        for (int l = 0; l < 8; ++l) {
            int j = 2 * t + l * 512;
            ushort2 p = *(const ushort2*)&drow[j];
            if (lab_s[j] == li && j != i) {
                float J = __logf(rbi + rns_s[j]) + h2f(p.x);
                float h = fmaxf(J, 0.f);
                local += h * h;
            }
            if (lab_s[j + 1] == li && (j + 1) != i) {
                float J = __logf(rbi + rns_s[j + 1]) + h2f(p.y);
                float h = fmaxf(J, 0.f);
                local += h * h;
            }
        }
    }
    #pragma unroll
    for (int o = 32; o > 0; o >>= 1) local += __shfl_down(local, o);
    __shared__ float part[4];
    if ((t & 63) == 0) part[t >> 6] = local;
    __syncthreads();
    if (t == 0) atomicAdd(loss_sum, part[0] + part[1] + part[2] + part[3]);
}

// ---------------------------------------------------------------------------
__global__ __launch_bounds__(256) void finalize_kernel(const int* __restrict__ labels,
                                                       const float* __restrict__ loss_sum,
                                                       float* __restrict__ out) {
    __shared__ int hist[16];
    int t = threadIdx.x;
    if (t < 16) hist[t] = 0;
    __syncthreads();
    for (int i = t; i < NROW; i += 256) atomicAdd(&hist[labels[i] & 15], 1);
    __syncthreads();
    if (t == 0) {
        long long np = 0;
        for (int c = 0; c < 16; ++c) np += (long long)hist[c] * (long long)(hist[c] - 1);
        out[0] = loss_sum[0] / (2.0f * (float)np);
    }
}

// ---------------------------------------------------------------------------
extern "C" void kernel_launch(void* const* d_in, const int* in_sizes, int n_in,
                              void* d_out, int out_size, void* d_ws, size_t ws_size,
                              hipStream_t stream) {
    const float* a      = (const float*)d_in[0];
    const float* b      = (const float*)d_in[1];
    const int*   labels = (const int*)d_in[2];
    float* out = (float*)d_out;

    // ws: abf(8MB) | bbf(8MB) | na,nb,rns,loss(+pad) | Dws(32MB fp16)
    unsigned short* abf = (unsigned short*)d_ws;
    unsigned short* bbf = abf + (size_t)NROW * FDIM;
    float* fws  = (float*)(bbf + (size_t)NROW * FDIM);
    float* na   = fws;
    float* nb   = fws + NROW;
    float* rns  = fws + 2 * NROW;
    float* loss = fws + 3 * NROW;
    unsigned short* Dws = (unsigned short*)(fws + 3 * NROW + 4);   // 16B aligned

    size_t need = ((char*)Dws - (char*)d_ws) + (size_t)NROW * NROW * 2;

    prep_kernel<<<NROW, 64, 0, stream>>>(a, b, abf, bbf, na, nb, rns, loss);

    dim3 grid((NROW / 128) * (NROW / 128));
    if (ws_size >= need) {
        pass_mfma<0><<<grid, 256, 0, stream>>>(abf, bbf, labels, na, nb, rns, Dws, loss);
        pass2_light<<<NROW / 16, 256, 0, stream>>>(Dws, labels, rns, loss);
    } else {
        pass_mfma<1><<<grid, 256, 0, stream>>>(abf, bbf, labels, na, nb, rns, Dws, loss);
        pass_mfma<2><<<grid, 256, 0, stream>>>(abf, bbf, labels, na, nb, rns, Dws, loss);
    }

    finalize_kernel<<<1, 256, 0, stream>>>(labels, loss, out);
}

// Round 5
// 145.830 us; speedup vs baseline: 3.8510x; 1.1576x over previous
//
#include <hip/hip_runtime.h>
#include <math.h>

#define NROW 4096
#define FDIM 512
#define MARGIN 1.0f

typedef __attribute__((ext_vector_type(8))) short short8;
typedef __attribute__((ext_vector_type(4))) float floatx4;

__device__ inline unsigned short f2bf(float x) {
    unsigned u = __float_as_uint(x);
    return (unsigned short)((u + 0x7FFFu + ((u >> 16) & 1u)) >> 16);
}
__device__ inline float h2f(unsigned short u) {
    _Float16 h; __builtin_memcpy(&h, &u, 2); return (float)h;
}
__device__ inline unsigned short f2h(float f) {
    _Float16 h = (_Float16)f; unsigned short u; __builtin_memcpy(&u, &h, 2); return u;
}

// ---------------------------------------------------------------------------
// Fused prep: bf16 convert + row norms + zero rns/loss. One wave per row.
// ---------------------------------------------------------------------------
__global__ __launch_bounds__(64) void prep_kernel(
    const float* __restrict__ a, const float* __restrict__ b,
    unsigned short* __restrict__ abf, unsigned short* __restrict__ bbf,
    float* __restrict__ na, float* __restrict__ nb,
    float* __restrict__ rns, float* __restrict__ loss) {
    int row  = blockIdx.x;
    int lane = threadIdx.x;
    const float4* a4 = (const float4*)(a + (size_t)row * FDIM);
    const float4* b4 = (const float4*)(b + (size_t)row * FDIM);
    ushort4* au = (ushort4*)(abf + (size_t)row * FDIM);
    ushort4* bu = (ushort4*)(bbf + (size_t)row * FDIM);
    float sa = 0.f, sb = 0.f;
    #pragma unroll
    for (int f = lane; f < FDIM / 4; f += 64) {
        float4 va = a4[f];
        float4 vb = b4[f];
        sa += va.x * va.x + va.y * va.y + va.z * va.z + va.w * va.w;
        sb += vb.x * vb.x + vb.y * vb.y + vb.z * vb.z + vb.w * vb.w;
        ushort4 ua = { f2bf(va.x), f2bf(va.y), f2bf(va.z), f2bf(va.w) };
        ushort4 ub = { f2bf(vb.x), f2bf(vb.y), f2bf(vb.z), f2bf(vb.w) };
        au[f] = ua;
        bu[f] = ub;
    }
    #pragma unroll
    for (int o = 32; o > 0; o >>= 1) {
        sa += __shfl_down(sa, o);
        sb += __shfl_down(sb, o);
    }
    if (lane == 0) {
        na[row] = sa;
        nb[row] = sb;
        rns[row] = 0.f;
        if (row == 0) loss[0] = 0.f;
    }
}

// ---------------------------------------------------------------------------
// MFMA pass: 128x128 tile of S = b @ a^T, BK=64 (two BK=32 sub-buffers per
// barrier), 4 waves in 2x2, 16x16x32 bf16 MFMA.
// MODE 0: phase1 (negsum) + store D tile (fp16) to workspace
// MODE 1: phase1 only                   (fallback when ws too small)
// MODE 2: phase2 recompute + hinge^2    (fallback)
// ---------------------------------------------------------------------------
template <int MODE>
__global__ __launch_bounds__(256) void pass_mfma(
    const unsigned short* __restrict__ abf, const unsigned short* __restrict__ bbf,
    const int* __restrict__ labels,
    const float* __restrict__ na, const float* __restrict__ nb,
    float* __restrict__ rns, unsigned short* __restrict__ Dws,
    float* __restrict__ loss_sum)
{
    // arena: 4 x 8KB k-major sub-tiles during GEMM; fp16 D tile (stride 136,
    // bank-conflict-free transpose) in the epilogue. 34.8 KB.
    __shared__ __align__(16) unsigned short smem[17408];
    unsigned short* As0 = smem;
    unsigned short* As1 = smem + 4096;
    unsigned short* Bs0 = smem + 8192;
    unsigned short* Bs1 = smem + 12288;
    __shared__ int   li_s[128], lj_s[128];
    __shared__ float nb_s[128], na_s[128], rbi_s[128], rbj_s[128];

    const int t    = threadIdx.x;
    const int lane = t & 63;
    const int w    = t >> 6;
    const int wi   = w >> 1, wj = w & 1;
    // supertile swizzle: 8x8 blocks per supertile for XCD/L2 locality
    const int bid  = blockIdx.x;
    const int sup  = bid >> 6, loc = bid & 63;
    const int by   = ((sup >> 2) << 3) | (loc >> 3);
    const int bx   = ((sup & 3) << 3) | (loc & 7);
    const int ti   = by * 128;           // b-row (i) origin
    const int tj   = bx * 128;           // a-row (j) origin
    const int lr   = lane & 15;
    const int lq   = lane >> 4;

    floatx4 acc[4][4];
    #pragma unroll
    for (int i = 0; i < 4; ++i)
        #pragma unroll
        for (int j = 0; j < 4; ++j)
            acc[i][j] = (floatx4){0.f, 0.f, 0.f, 0.f};

    if (t < 128) {
        li_s[t] = labels[ti + t];
        nb_s[t] = nb[ti + t];
        if (MODE == 2) rbi_s[t] = rns[ti + t];
    } else {
        int u = t - 128;
        lj_s[u] = labels[tj + u];
        na_s[u] = na[tj + u];
        if (MODE == 2) rbj_s[u] = rns[tj + u];
    }

    for (int kk = 0; kk < FDIM; kk += 64) {
        #pragma unroll
        for (int l = 0; l < 2; ++l) {
            int c   = t + l * 256;       // 0..511
            int row = c >> 2;
            int q   = c & 3;
            size_t ga = (size_t)(tj + row) * FDIM + kk + q * 8;
            size_t gb = (size_t)(ti + row) * FDIM + kk + q * 8;
            __builtin_amdgcn_global_load_lds(
                (const __attribute__((address_space(1))) unsigned int*)(abf + ga),
                (__attribute__((address_space(3))) unsigned int*)(As0 + c * 8), 16, 0, 0);
            __builtin_amdgcn_global_load_lds(
                (const __attribute__((address_space(1))) unsigned int*)(abf + ga + 32),
                (__attribute__((address_space(3))) unsigned int*)(As1 + c * 8), 16, 0, 0);
            __builtin_amdgcn_global_load_lds(
                (const __attribute__((address_space(1))) unsigned int*)(bbf + gb),
                (__attribute__((address_space(3))) unsigned int*)(Bs0 + c * 8), 16, 0, 0);
            __builtin_amdgcn_global_load_lds(
                (const __attribute__((address_space(1))) unsigned int*)(bbf + gb + 32),
                (__attribute__((address_space(3))) unsigned int*)(Bs1 + c * 8), 16, 0, 0);
        }
        __syncthreads();

        {   // k half 0
            short8 af[4], bf[4];
            #pragma unroll
            for (int ri = 0; ri < 4; ++ri)
                af[ri] = *(const short8*)&Bs0[(wi * 64 + ri * 16 + lr) * 32 + lq * 8];
            #pragma unroll
            for (int rj = 0; rj < 4; ++rj)
                bf[rj] = *(const short8*)&As0[(wj * 64 + rj * 16 + lr) * 32 + lq * 8];
            #pragma unroll
            for (int ri = 0; ri < 4; ++ri)
                #pragma unroll
                for (int rj = 0; rj < 4; ++rj)
                    acc[ri][rj] = __builtin_amdgcn_mfma_f32_16x16x32_bf16(
                        af[ri], bf[rj], acc[ri][rj], 0, 0, 0);
        }
        {   // k half 1
            short8 af[4], bf[4];
            #pragma unroll
            for (int ri = 0; ri < 4; ++ri)
                af[ri] = *(const short8*)&Bs1[(wi * 64 + ri * 16 + lr) * 32 + lq * 8];
            #pragma unroll
            for (int rj = 0; rj < 4; ++rj)
                bf[rj] = *(const short8*)&As1[(wj * 64 + rj * 16 + lr) * 32 + lq * 8];
            #pragma unroll
            for (int ri = 0; ri < 4; ++ri)
                #pragma unroll
                for (int rj = 0; rj < 4; ++rj)
                    acc[ri][rj] = __builtin_amdgcn_mfma_f32_16x16x32_bf16(
                        af[ri], bf[rj], acc[ri][rj], 0, 0, 0);
        }
        __syncthreads();
    }

    if (MODE == 0 || MODE == 1) {
        // phase-1 epilogue: C/D layout col = lane&15, row = quad*4 + reg
        unsigned short* D_s = smem;       // 128 x 136-stride fp16 tile
        #pragma unroll
        for (int ri = 0; ri < 4; ++ri) {
            float rs[4] = {0.f, 0.f, 0.f, 0.f};
            #pragma unroll
            for (int rj = 0; rj < 4; ++rj) {
                int   jl  = wj * 64 + rj * 16 + lr;
                float naj = na_s[jl];
                int   ljv = lj_s[jl];
                #pragma unroll
                for (int r = 0; r < 4; ++r) {
                    int   il  = wi * 64 + ri * 16 + lq * 4 + r;
                    float dsq = nb_s[il] + naj - 2.f * acc[ri][rj][r];
                    float D   = sqrtf(fmaxf(dsq, 0.f));
                    if (li_s[il] != ljv) rs[r] += __expf(MARGIN - D);
                    if (MODE == 0) D_s[il * 136 + jl] = f2h(D);
                }
            }
            #pragma unroll
            for (int r = 0; r < 4; ++r) {
                #pragma unroll
                for (int o = 8; o > 0; o >>= 1) rs[r] += __shfl_down(rs[r], o, 16);
            }
            if (lr == 0) {
                #pragma unroll
                for (int r = 0; r < 4; ++r)
                    atomicAdd(&rns[ti + wi * 64 + ri * 16 + lq * 4 + r], rs[r]);
            }
        }
        if (MODE == 0) {
            __syncthreads();
            // coalesced fp16 D tile writeout, 16B per thread-chunk
            #pragma unroll
            for (int l = 0; l < 8; ++l) {
                int c  = t + l * 256;     // 0..2047
                int r  = c >> 4;
                int cw = c & 15;
                *(short8*)&Dws[(size_t)(ti + r) * NROW + tj + cw * 8] =
                    *(const short8*)&D_s[r * 136 + cw * 8];
            }
        }
    } else {
        // phase-2 recompute epilogue
        float local = 0.f;
        #pragma unroll
        for (int ri = 0; ri < 4; ++ri)
            #pragma unroll
            for (int rj = 0; rj < 4; ++rj) {
                int jl  = wj * 64 + rj * 16 + lr;
                int ljv = lj_s[jl];
                float naj = na_s[jl], rbj = rbj_s[jl];
                #pragma unroll
                for (int r = 0; r < 4; ++r) {
                    int il = wi * 64 + ri * 16 + lq * 4 + r;
                    int i  = ti + il, j = tj + jl;
                    if (li_s[il] == ljv && i != j) {
                        float dsq = nb_s[il] + naj - 2.f * acc[ri][rj][r];
                        float D   = sqrtf(fmaxf(dsq, 0.f));
                        float J   = __logf(rbi_s[il] + rbj) + D;
                        float h   = fmaxf(J, 0.f);
                        local += h * h;
                    }
                }
            }
        #pragma unroll
        for (int o = 32; o > 0; o >>= 1) local += __shfl_down(local, o);
        __shared__ float part[4];
        if (lane == 0) part[w] = local;
        __syncthreads();
        if (t == 0) atomicAdd(loss_sum, part[0] + part[1] + part[2] + part[3]);
    }
}

// ---------------------------------------------------------------------------
// Phase-2 sweep over stored D (fp16): flat grid-stride, coalesced short8
// chunks; labels[i]/rns[i] block-uniform; labels[j]/rns[j] L1-resident.
// 2048 blocks x 256 threads x 4 chunks of 8 = 16.8M pairs.
// ---------------------------------------------------------------------------
__global__ __launch_bounds__(256) void pass2_sweep(
    const unsigned short* __restrict__ Dws, const int* __restrict__ labels,
    const float* __restrict__ rns, float* __restrict__ loss_sum)
{
    const int t = threadIdx.x;
    float local = 0.f;
    #pragma unroll
    for (int l = 0; l < 4; ++l) {
        int c  = blockIdx.x * 256 + t + l * 524288;  // chunk id, 512 chunks/row
        int i  = c >> 9;
        int j0 = (c & 511) * 8;
        int   li  = labels[i];
        float rbi = rns[i];
        short8 d8 = *(const short8*)&Dws[(size_t)i * NROW + j0];
        int4   la = *(const int4*)&labels[j0];
        int4   lb = *(const int4*)&labels[j0 + 4];
        float4 ra = *(const float4*)&rns[j0];
        float4 rb = *(const float4*)&rns[j0 + 4];
        int   labs[8] = {la.x, la.y, la.z, la.w, lb.x, lb.y, lb.z, lb.w};
        float rnsj[8] = {ra.x, ra.y, ra.z, ra.w, rb.x, rb.y, rb.z, rb.w};
        #pragma unroll
        for (int e = 0; e < 8; ++e) {
            int j = j0 + e;
            if (labs[e] == li && j != i) {
                float J = __logf(rbi + rnsj[e]) + h2f((unsigned short)d8[e]);
                float h = fmaxf(J, 0.f);
                local += h * h;
            }
        }
    }
    #pragma unroll
    for (int o = 32; o > 0; o >>= 1) local += __shfl_down(local, o);
    __shared__ float part[4];
    if ((t & 63) == 0) part[t >> 6] = local;
    __syncthreads();
    if (t == 0) atomicAdd(loss_sum, part[0] + part[1] + part[2] + part[3]);
}

// ---------------------------------------------------------------------------
__global__ __launch_bounds__(256) void finalize_kernel(const int* __restrict__ labels,
                                                       const float* __restrict__ loss_sum,
                                                       float* __restrict__ out) {
    __shared__ int hist[16];
    int t = threadIdx.x;
    if (t < 16) hist[t] = 0;
    __syncthreads();
    for (int i = t; i < NROW; i += 256) atomicAdd(&hist[labels[i] & 15], 1);
    __syncthreads();
    if (t == 0) {
        long long np = 0;
        for (int c = 0; c < 16; ++c) np += (long long)hist[c] * (long long)(hist[c] - 1);
        out[0] = loss_sum[0] / (2.0f * (float)np);
    }
}

// ---------------------------------------------------------------------------
extern "C" void kernel_launch(void* const* d_in, const int* in_sizes, int n_in,
                              void* d_out, int out_size, void* d_ws, size_t ws_size,
                              hipStream_t stream) {
    const float* a      = (const float*)d_in[0];
    const float* b      = (const float*)d_in[1];
    const int*   labels = (const int*)d_in[2];
    float* out = (float*)d_out;

    // ws: abf(8MB) | bbf(8MB) | na,nb,rns,loss(+pad) | Dws(32MB fp16)
    unsigned short* abf = (unsigned short*)d_ws;
    unsigned short* bbf = abf + (size_t)NROW * FDIM;
    float* fws  = (float*)(bbf + (size_t)NROW * FDIM);
    float* na   = fws;
    float* nb   = fws + NROW;
    float* rns  = fws + 2 * NROW;
    float* loss = fws + 3 * NROW;
    unsigned short* Dws = (unsigned short*)(fws + 3 * NROW + 4);   // 16B aligned

    size_t need = ((char*)Dws - (char*)d_ws) + (size_t)NROW * NROW * 2;

    prep_kernel<<<NROW, 64, 0, stream>>>(a, b, abf, bbf, na, nb, rns, loss);

    dim3 grid((NROW / 128) * (NROW / 128));
    if (ws_size >= need) {
        pass_mfma<0><<<grid, 256, 0, stream>>>(abf, bbf, labels, na, nb, rns, Dws, loss);
        pass2_sweep<<<2048, 256, 0, stream>>>(Dws, labels, rns, loss);
    } else {
        pass_mfma<1><<<grid, 256, 0, stream>>>(abf, bbf, labels, na, nb, rns, Dws, loss);
        pass_mfma<2><<<grid, 256, 0, stream>>>(abf, bbf, labels, na, nb, rns, Dws, loss);
    }

    finalize_kernel<<<1, 256, 0, stream>>>(labels, loss, out);
}